// Round 8
// baseline (220.755 us; speedup 1.0000x reference)
//
#include <hip/hip_runtime.h>
#include <hip/hip_bf16.h>

// GCN 2-layer, MI355X — MFMA version.
// Round-7 (171.6us) was VALU-issue bound: ~256 of ~300 VALU ops/lane/node were
// the scalar z@W^T matmul. This round: per-wave 16-node tiles, C[16x64] =
// A[16x128] @ B[128x64] via 16x mfma_f32_16x16x32_bf16; W preloaded once per
// wave into B-fragments (VGPRs); gather uses 2-rows-per-load dwords; z staged
// in a private per-wave LDS A-tile (no barriers anywhere).

#define N_NODES 50000
#define DEG 16
#define DIM 64
#define NTILES 3125   // N_NODES / 16

typedef __attribute__((ext_vector_type(8))) short short8;   // 8 bf16 (4 VGPR)
typedef __attribute__((ext_vector_type(4))) float f32x4;    // MFMA acc

__device__ __forceinline__ unsigned short f2b(float f) {    // RNE f32->bf16
  unsigned int u = __float_as_uint(f);
  u = (u + 0x7FFFu + ((u >> 16) & 1u)) >> 16;
  return (unsigned short)u;
}

__global__ void cast_bf16(const float* __restrict__ in, unsigned short* __restrict__ out, int n4) {
  const int i = blockIdx.x * 256 + threadIdx.x;
  if (i < n4) {
    const float4 v = reinterpret_cast<const float4*>(in)[i];
    ushort4 o4;
    o4.x = f2b(v.x); o4.y = f2b(v.y); o4.z = f2b(v.z); o4.w = f2b(v.w);
    reinterpret_cast<ushort4*>(out)[i] = o4;
  }
}

// ---- shared per-layer body as a macro-free pattern, duplicated for the two
// epilogues (keeps template surface minimal). ----

// Gather one neighbor row for this lane's half-node, accumulate 2 features.
#define GATH(RA, RB, PLO, PHI)                                         \
  {                                                                    \
    const int _row = half ? (RB) : (RA);                               \
    const unsigned int _u = ftp[_row * 32 + c];                        \
    PLO += __uint_as_float(_u << 16);                                  \
    PHI += __uint_as_float(_u & 0xFFFF0000u);                          \
  }

#define GATHER_AND_STAGE()                                                        \
  _Pragma("unroll 2")                                                             \
  for (int p = 0; p < 8; ++p) {                                                   \
    const int rA = (base + 2 * p) * DEG;                                          \
    const int4 ia0 = *(const int4*)(nbr + rA);                                    \
    const int4 ia1 = *(const int4*)(nbr + rA + 4);                                \
    const int4 ia2 = *(const int4*)(nbr + rA + 8);                                \
    const int4 ia3 = *(const int4*)(nbr + rA + 12);                               \
    const int4 ib0 = *(const int4*)(nbr + rA + 16);                               \
    const int4 ib1 = *(const int4*)(nbr + rA + 20);                               \
    const int4 ib2 = *(const int4*)(nbr + rA + 24);                               \
    const int4 ib3 = *(const int4*)(nbr + rA + 28);                               \
    float plo0 = 0.f, phi0 = 0.f, plo1 = 0.f, phi1 = 0.f;                         \
    GATH(ia0.x, ib0.x, plo0, phi0) GATH(ia0.y, ib0.y, plo1, phi1)                 \
    GATH(ia0.z, ib0.z, plo0, phi0) GATH(ia0.w, ib0.w, plo1, phi1)                 \
    GATH(ia1.x, ib1.x, plo0, phi0) GATH(ia1.y, ib1.y, plo1, phi1)                 \
    GATH(ia1.z, ib1.z, plo0, phi0) GATH(ia1.w, ib1.w, plo1, phi1)                 \
    GATH(ia2.x, ib2.x, plo0, phi0) GATH(ia2.y, ib2.y, plo1, phi1)                 \
    GATH(ia2.z, ib2.z, plo0, phi0) GATH(ia2.w, ib2.w, plo1, phi1)                 \
    GATH(ia3.x, ib3.x, plo0, phi0) GATH(ia3.y, ib3.y, plo1, phi1)                 \
    GATH(ia3.z, ib3.z, plo0, phi0) GATH(ia3.w, ib3.w, plo1, phi1)                 \
    const float plo = plo0 + plo1, phi = phi0 + phi1;                             \
    const unsigned int un = ftp[(base + 2 * p + half) * 32 + c];                  \
    const float nlo = __uint_as_float(un << 16);                                  \
    const float nhi = __uint_as_float(un & 0xFFFF0000u);                          \
    const float z1lo = nlo + plo, z1hi = nhi + phi;                               \
    const float z2lo = nlo * plo, z2hi = nhi * phi;                               \
    unsigned int z1p, z2p;                                                        \
    asm("v_cvt_pk_bf16_f32 %0, %1, %2" : "=v"(z1p) : "v"(z1lo), "v"(z1hi));       \
    asm("v_cvt_pk_bf16_f32 %0, %1, %2" : "=v"(z2p) : "v"(z2lo), "v"(z2hi));       \
    const int r = 2 * p + half;                                                   \
    Az[wid][r * 64 + c] = z1p;                                                    \
    Az[wid][r * 64 + 32 + c] = z2p;                                               \
  }

#define PRELOAD_W()                                                               \
  short8 Bf[4][4];                                                                \
  {                                                                               \
    const int wn = lane & 15, wg = lane >> 4;                                     \
    _Pragma("unroll")                                                             \
    for (int ct = 0; ct < 4; ++ct) {                                              \
      _Pragma("unroll")                                                           \
      for (int ks = 0; ks < 4; ++ks) {                                            \
        const float* wp = W + (ct * 16 + wn) * 128 + ks * 32 + wg * 8;            \
        const float4 w0 = *(const float4*)wp;                                     \
        const float4 w1 = *(const float4*)(wp + 4);                               \
        short8 f;                                                                 \
        f[0] = (short)f2b(w0.x); f[1] = (short)f2b(w0.y);                         \
        f[2] = (short)f2b(w0.z); f[3] = (short)f2b(w0.w);                         \
        f[4] = (short)f2b(w1.x); f[5] = (short)f2b(w1.y);                         \
        f[6] = (short)f2b(w1.z); f[7] = (short)f2b(w1.w);                         \
        Bf[ct][ks] = f;                                                           \
      }                                                                           \
    }                                                                             \
  }

#define MFMA_ACCUM()                                                              \
  f32x4 ac0 = {0.f, 0.f, 0.f, 0.f}, ac1 = ac0, ac2 = ac0, ac3 = ac0;             \
  {                                                                               \
    const int arow = lane & 15, agrp = lane >> 4;                                 \
    _Pragma("unroll")                                                             \
    for (int ks = 0; ks < 4; ++ks) {                                              \
      const short8 a = *(const short8*)&Az[wid][arow * 64 + ks * 16 + agrp * 4];  \
      ac0 = __builtin_amdgcn_mfma_f32_16x16x32_bf16(a, Bf[0][ks], ac0, 0, 0, 0);  \
      ac1 = __builtin_amdgcn_mfma_f32_16x16x32_bf16(a, Bf[1][ks], ac1, 0, 0, 0);  \
      ac2 = __builtin_amdgcn_mfma_f32_16x16x32_bf16(a, Bf[2][ks], ac2, 0, 0, 0);  \
      ac3 = __builtin_amdgcn_mfma_f32_16x16x32_bf16(a, Bf[3][ks], ac3, 0, 0, 0);  \
    }                                                                             \
  }

__global__ void gcn_mfma1(const unsigned short* __restrict__ ftb,
                          const float* __restrict__ W,
                          const int* __restrict__ nbr,
                          unsigned short* __restrict__ outb) {
  __shared__ unsigned int Az[4][1024];   // per-wave A-tile: 16 rows x 128 bf16
  const int tid = threadIdx.x;
  const int lane = tid & 63, wid = tid >> 6;
  const int t = blockIdx.x * 4 + wid;
  if (t >= NTILES) return;
  const int base = t * 16;
  const int half = lane >> 5, c = lane & 31;
  const unsigned int* ftp = (const unsigned int*)ftb;

  PRELOAD_W();
  GATHER_AND_STAGE();
  MFMA_ACCUM();

  // C: col = lane&15 (feature within col-tile), row = (lane>>4)*4 + reg (node)
  const int colf = lane & 15, rgrp = lane >> 4;
#define ST1(AC, CT)                                                          \
  {                                                                          \
    _Pragma("unroll")                                                        \
    for (int r = 0; r < 4; ++r)                                              \
      outb[(base + rgrp * 4 + r) * 64 + CT * 16 + colf] =                    \
          f2b(fmaxf(AC[r], 0.f));                                            \
  }
  ST1(ac0, 0) ST1(ac1, 1) ST1(ac2, 2) ST1(ac3, 3)
#undef ST1
}

__global__ void gcn_mfma2(const unsigned short* __restrict__ ftb,
                          const float* __restrict__ W,
                          const int* __restrict__ nbr,
                          float* __restrict__ out) {
  __shared__ unsigned int Az[4][1024];
  const int tid = threadIdx.x;
  const int lane = tid & 63, wid = tid >> 6;
  const int t = blockIdx.x * 4 + wid;
  if (t >= NTILES) return;
  const int base = t * 16;
  const int half = lane >> 5, c = lane & 31;
  const unsigned int* ftp = (const unsigned int*)ftb;

  PRELOAD_W();
  GATHER_AND_STAGE();
  MFMA_ACCUM();

  // relu, then per-node L2 norm: node's features for fixed reg r live in the
  // 16 lanes of this row-group (cols) x 4 col-tiles.
  float v0[4], v1[4], v2[4], v3[4];   // [ct fixed per array][reg]
  float s0 = 0.f, s1 = 0.f, s2 = 0.f, s3 = 0.f;
#pragma unroll
  for (int r = 0; r < 4; ++r) {
    v0[r] = fmaxf(ac0[r], 0.f);
    v1[r] = fmaxf(ac1[r], 0.f);
    v2[r] = fmaxf(ac2[r], 0.f);
    v3[r] = fmaxf(ac3[r], 0.f);
  }
  s0 = v0[0]*v0[0] + v1[0]*v1[0] + v2[0]*v2[0] + v3[0]*v3[0];
  s1 = v0[1]*v0[1] + v1[1]*v1[1] + v2[1]*v2[1] + v3[1]*v3[1];
  s2 = v0[2]*v0[2] + v1[2]*v1[2] + v2[2]*v2[2] + v3[2]*v3[2];
  s3 = v0[3]*v0[3] + v1[3]*v1[3] + v2[3]*v2[3] + v3[3]*v3[3];
#pragma unroll
  for (int w = 1; w < 16; w <<= 1) {   // reduce over the 16 col-lanes
    s0 += __shfl_xor(s0, w, 64);
    s1 += __shfl_xor(s1, w, 64);
    s2 += __shfl_xor(s2, w, 64);
    s3 += __shfl_xor(s3, w, 64);
  }
  const float k0 = 1.f / fmaxf(sqrtf(s0), 1e-12f);
  const float k1 = 1.f / fmaxf(sqrtf(s1), 1e-12f);
  const float k2 = 1.f / fmaxf(sqrtf(s2), 1e-12f);
  const float k3 = 1.f / fmaxf(sqrtf(s3), 1e-12f);

  const int colf = lane & 15, rgrp = lane >> 4;
#define ST2(VARR, CT)                                                        \
  {                                                                          \
    out[(base + rgrp * 4 + 0) * 64 + CT * 16 + colf] = VARR[0] * k0;         \
    out[(base + rgrp * 4 + 1) * 64 + CT * 16 + colf] = VARR[1] * k1;         \
    out[(base + rgrp * 4 + 2) * 64 + CT * 16 + colf] = VARR[2] * k2;         \
    out[(base + rgrp * 4 + 3) * 64 + CT * 16 + colf] = VARR[3] * k3;         \
  }
  ST2(v0, 0) ST2(v1, 1) ST2(v2, 2) ST2(v3, 3)
#undef ST2
}

extern "C" void kernel_launch(void* const* d_in, const int* in_sizes, int n_in,
                              void* d_out, int out_size, void* d_ws, size_t ws_size,
                              hipStream_t stream) {
  const float* ft0;
  const float* W1;
  const float* W2;
  const int*   nbr;
  if (in_sizes[0] == N_NODES * DIM) {          // insertion order
    ft0 = (const float*)d_in[0];
    W1  = (const float*)d_in[1];
    W2  = (const float*)d_in[2];
    nbr = (const int*)d_in[3];
  } else {                                      // alphabetical fallback
    W1  = (const float*)d_in[0];
    W2  = (const float*)d_in[1];
    ft0 = (const float*)d_in[2];
    nbr = (const int*)d_in[3];
  }

  unsigned short* ftb0 = (unsigned short*)d_ws;          // 6.4 MB bf16 ft_lv0
  unsigned short* ft1b = ftb0 + (size_t)N_NODES * DIM;   // 6.4 MB bf16 ft_lv1
  float* out = (float*)d_out;

  const int n4 = (N_NODES * DIM) / 4;
  cast_bf16<<<dim3((n4 + 255) / 256), dim3(256), 0, stream>>>(ft0, ftb0, n4);

  const int nblk = (NTILES + 3) / 4;            // 782 blocks x 4 waves = 3128
  gcn_mfma1<<<dim3(nblk), dim3(256), 0, stream>>>(ftb0, W1, nbr, ft1b);
  gcn_mfma2<<<dim3(nblk), dim3(256), 0, stream>>>(ft1b, W2, nbr, out);
}

// Round 12
// 116.356 us; speedup vs baseline: 1.8972x; 1.8972x over previous
//
#include <hip/hip_runtime.h>
#include <hip/hip_bf16.h>

// GCN 2-layer, MI355X — MFMA v2.
// Round-8 (220us) was latency-bound (VALUBusy 3.8%, occ 12%, VGPR 64): gather
// serialized at vmcnt(0) per load, W re-converted per wave, 2B scatter stores
// (WRITE 53MB for 6.4MB output). v2: launch_bounds VGPR headroom + batched
// gather loads, W pre-converted once to B-fragments, LDS-bounced coalesced
// C-stores, XOR-swizzled A-tile (kills 16-way ds_read_b128 conflict).

#define N_NODES 50000
#define DEG 16
#define DIM 64
#define NTILES 3125   // N_NODES / 16

typedef __attribute__((ext_vector_type(8))) short short8;           // 8 bf16
typedef __attribute__((ext_vector_type(8))) unsigned short ushort8; // 16B
typedef __attribute__((ext_vector_type(4))) float f32x4;

__device__ __forceinline__ unsigned short f2b(float f) {  // RNE f32->bf16
  unsigned int u = __float_as_uint(f);
  u = (u + 0x7FFFu + ((u >> 16) & 1u)) >> 16;
  return (unsigned short)u;
}
#define LOF(u) __uint_as_float((u) << 16)
#define HIF(u) __uint_as_float((u) & 0xFFFF0000u)

__global__ void cast_bf16(const float* __restrict__ in, unsigned short* __restrict__ out, int n4) {
  const int i = blockIdx.x * 256 + threadIdx.x;
  if (i < n4) {
    const float4 v = reinterpret_cast<const float4*>(in)[i];
    ushort4 o4;
    o4.x = f2b(v.x); o4.y = f2b(v.y); o4.z = f2b(v.z); o4.w = f2b(v.w);
    reinterpret_cast<ushort4*>(out)[i] = o4;
  }
}

// Convert W1,W2 once into per-lane MFMA B-fragments:
// frag f = ct*4+ks, lane l (wn=l&15 col, wg=l>>4): elems W[ct*16+wn][ks*32+wg*8+e]
// stored contiguously at Wb[((which*16+f)*64+l)*8 ..] -> one 16B load per frag.
__global__ void prep_w(const float* __restrict__ W1, const float* __restrict__ W2,
                       unsigned short* __restrict__ Wb) {
  const int task = blockIdx.x * 256 + threadIdx.x;
  if (task >= 2048) return;
  const int which = task >> 10;
  const int f = (task >> 6) & 15;
  const int l = task & 63;
  const int ct = f >> 2, ks = f & 3;
  const int wn = l & 15, wg = l >> 4;
  const float* W = which ? W2 : W1;
  const float* wp = W + (ct * 16 + wn) * 128 + ks * 32 + wg * 8;
  const float4 w0 = *(const float4*)wp;
  const float4 w1 = *(const float4*)(wp + 4);
  ushort8 o;
  o[0] = f2b(w0.x); o[1] = f2b(w0.y); o[2] = f2b(w0.z); o[3] = f2b(w0.w);
  o[4] = f2b(w1.x); o[5] = f2b(w1.y); o[6] = f2b(w1.z); o[7] = f2b(w1.w);
  *(ushort8*)(Wb + ((size_t)(which * 16 + f) * 64 + l) * 8) = o;
}

// Batched gather: issue all 16 row loads of a node-pair, THEN sum (x2 unroll).
#define GATHER_AND_STAGE()                                                     \
  _Pragma("unroll 2")                                                          \
  for (int p = 0; p < 8; ++p) {                                                \
    const int rA = (base + 2 * p) * DEG;                                       \
    const int4 ia0 = *(const int4*)(nbr + rA);                                 \
    const int4 ia1 = *(const int4*)(nbr + rA + 4);                             \
    const int4 ia2 = *(const int4*)(nbr + rA + 8);                             \
    const int4 ia3 = *(const int4*)(nbr + rA + 12);                            \
    const int4 ib0 = *(const int4*)(nbr + rA + 16);                            \
    const int4 ib1 = *(const int4*)(nbr + rA + 20);                            \
    const int4 ib2 = *(const int4*)(nbr + rA + 24);                            \
    const int4 ib3 = *(const int4*)(nbr + rA + 28);                            \
    const unsigned int un  = ftp[(base + 2 * p + half) * 32 + c];              \
    const unsigned int v0  = ftp[(half ? ib0.x : ia0.x) * 32 + c];             \
    const unsigned int v1  = ftp[(half ? ib0.y : ia0.y) * 32 + c];             \
    const unsigned int v2  = ftp[(half ? ib0.z : ia0.z) * 32 + c];             \
    const unsigned int v3  = ftp[(half ? ib0.w : ia0.w) * 32 + c];             \
    const unsigned int v4  = ftp[(half ? ib1.x : ia1.x) * 32 + c];             \
    const unsigned int v5  = ftp[(half ? ib1.y : ia1.y) * 32 + c];             \
    const unsigned int v6  = ftp[(half ? ib1.z : ia1.z) * 32 + c];             \
    const unsigned int v7  = ftp[(half ? ib1.w : ia1.w) * 32 + c];             \
    const unsigned int v8  = ftp[(half ? ib2.x : ia2.x) * 32 + c];             \
    const unsigned int v9  = ftp[(half ? ib2.y : ia2.y) * 32 + c];             \
    const unsigned int v10 = ftp[(half ? ib2.z : ia2.z) * 32 + c];             \
    const unsigned int v11 = ftp[(half ? ib2.w : ia2.w) * 32 + c];             \
    const unsigned int v12 = ftp[(half ? ib3.x : ia3.x) * 32 + c];             \
    const unsigned int v13 = ftp[(half ? ib3.y : ia3.y) * 32 + c];             \
    const unsigned int v14 = ftp[(half ? ib3.z : ia3.z) * 32 + c];             \
    const unsigned int v15 = ftp[(half ? ib3.w : ia3.w) * 32 + c];             \
    const float plo = (((LOF(v0) + LOF(v1)) + (LOF(v2) + LOF(v3))) +           \
                       ((LOF(v4) + LOF(v5)) + (LOF(v6) + LOF(v7)))) +          \
                      (((LOF(v8) + LOF(v9)) + (LOF(v10) + LOF(v11))) +         \
                       ((LOF(v12) + LOF(v13)) + (LOF(v14) + LOF(v15))));       \
    const float phi = (((HIF(v0) + HIF(v1)) + (HIF(v2) + HIF(v3))) +           \
                       ((HIF(v4) + HIF(v5)) + (HIF(v6) + HIF(v7)))) +          \
                      (((HIF(v8) + HIF(v9)) + (HIF(v10) + HIF(v11))) +         \
                       ((HIF(v12) + HIF(v13)) + (HIF(v14) + HIF(v15))));       \
    const float nlo = LOF(un), nhi = HIF(un);                                  \
    const float z1lo = nlo + plo, z1hi = nhi + phi;                            \
    const float z2lo = nlo * plo, z2hi = nhi * phi;                            \
    unsigned int z1p, z2p;                                                     \
    asm("v_cvt_pk_bf16_f32 %0, %1, %2" : "=v"(z1p) : "v"(z1lo), "v"(z1hi));    \
    asm("v_cvt_pk_bf16_f32 %0, %1, %2" : "=v"(z2p) : "v"(z2lo), "v"(z2hi));    \
    const int r = 2 * p + half;                                                \
    const int cs = c ^ ((r & 7) << 2);                                         \
    Az[wid][r * 64 + cs] = z1p;                                                \
    Az[wid][r * 64 + 32 + cs] = z2p;                                           \
  }

#define PRELOAD_W()                                                            \
  short8 Bf[4][4];                                                             \
  {                                                                            \
    const short8* wf = (const short8*)Wb;                                      \
    _Pragma("unroll")                                                          \
    for (int f = 0; f < 16; ++f) Bf[f >> 2][f & 3] = wf[f * 64 + lane];        \
  }

#define MFMA_ACCUM()                                                           \
  f32x4 ac0 = {0.f, 0.f, 0.f, 0.f}, ac1 = ac0, ac2 = ac0, ac3 = ac0;          \
  {                                                                            \
    const int arow = lane & 15, agrp = lane >> 4;                              \
    const int axor = (arow & 7) << 2;                                          \
    _Pragma("unroll")                                                          \
    for (int ks = 0; ks < 4; ++ks) {                                           \
      const short8 a =                                                         \
          *(const short8*)&Az[wid][arow * 64 + ((ks * 16 + agrp * 4) ^ axor)]; \
      ac0 = __builtin_amdgcn_mfma_f32_16x16x32_bf16(a, Bf[0][ks], ac0, 0, 0, 0);\
      ac1 = __builtin_amdgcn_mfma_f32_16x16x32_bf16(a, Bf[1][ks], ac1, 0, 0, 0);\
      ac2 = __builtin_amdgcn_mfma_f32_16x16x32_bf16(a, Bf[2][ks], ac2, 0, 0, 0);\
      ac3 = __builtin_amdgcn_mfma_f32_16x16x32_bf16(a, Bf[3][ks], ac3, 0, 0, 0);\
    }                                                                          \
  }

__global__ __launch_bounds__(256, 2)
void gcn_mfma1(const unsigned short* __restrict__ ftb,
               const unsigned short* __restrict__ Wb,
               const int* __restrict__ nbr,
               unsigned short* __restrict__ outb) {
  __shared__ unsigned int Az[4][1024];
  const int tid = threadIdx.x;
  const int lane = tid & 63, wid = tid >> 6;
  const int t = blockIdx.x * 4 + wid;
  if (t >= NTILES) return;
  const int base = t * 16;
  const int half = lane >> 5, c = lane & 31;
  const unsigned int* ftp = (const unsigned int*)ftb;

  GATHER_AND_STAGE();
  PRELOAD_W();
  MFMA_ACCUM();

  // C (col=lane&15, row=(lane>>4)*4+reg) -> LDS (XOR block swizzle) -> coalesced
  unsigned short* sh = (unsigned short*)&Az[wid][0];
  const int colf = lane & 15, rgrp = lane >> 4;
#define STAGE1(AC, CT)                                                         \
  _Pragma("unroll")                                                            \
  for (int rr = 0; rr < 4; ++rr)                                               \
    sh[(rgrp * 4 + rr) * 64 + (((CT)*16 + colf) ^ (rgrp << 4))] =              \
        f2b(fmaxf(AC[rr], 0.f));
  STAGE1(ac0, 0) STAGE1(ac1, 1) STAGE1(ac2, 2) STAGE1(ac3, 3)
#undef STAGE1
  const int row = lane >> 2, q = lane & 3;
  const int blk = q ^ (row >> 2);
  const ushort8 d0 = *(const ushort8*)&sh[row * 64 + q * 16];
  const ushort8 d1 = *(const ushort8*)&sh[row * 64 + q * 16 + 8];
  *(ushort8*)(outb + (base + row) * 64 + blk * 16) = d0;
  *(ushort8*)(outb + (base + row) * 64 + blk * 16 + 8) = d1;
}

__global__ __launch_bounds__(256, 2)
void gcn_mfma2(const unsigned short* __restrict__ ftb,
               const unsigned short* __restrict__ Wb,
               const int* __restrict__ nbr,
               float* __restrict__ out) {
  __shared__ unsigned int Az[4][1024];
  const int tid = threadIdx.x;
  const int lane = tid & 63, wid = tid >> 6;
  const int t = blockIdx.x * 4 + wid;
  if (t >= NTILES) return;
  const int base = t * 16;
  const int half = lane >> 5, c = lane & 31;
  const unsigned int* ftp = (const unsigned int*)ftb;

  GATHER_AND_STAGE();
  PRELOAD_W();
  MFMA_ACCUM();

  float v0[4], v1[4], v2[4], v3[4];
#pragma unroll
  for (int rr = 0; rr < 4; ++rr) {
    v0[rr] = fmaxf(ac0[rr], 0.f);
    v1[rr] = fmaxf(ac1[rr], 0.f);
    v2[rr] = fmaxf(ac2[rr], 0.f);
    v3[rr] = fmaxf(ac3[rr], 0.f);
  }
  float s0 = v0[0]*v0[0] + v1[0]*v1[0] + v2[0]*v2[0] + v3[0]*v3[0];
  float s1 = v0[1]*v0[1] + v1[1]*v1[1] + v2[1]*v2[1] + v3[1]*v3[1];
  float s2 = v0[2]*v0[2] + v1[2]*v1[2] + v2[2]*v2[2] + v3[2]*v3[2];
  float s3 = v0[3]*v0[3] + v1[3]*v1[3] + v2[3]*v2[3] + v3[3]*v3[3];
#pragma unroll
  for (int w = 1; w < 16; w <<= 1) {
    s0 += __shfl_xor(s0, w, 64);
    s1 += __shfl_xor(s1, w, 64);
    s2 += __shfl_xor(s2, w, 64);
    s3 += __shfl_xor(s3, w, 64);
  }
  const float kk[4] = {1.f / fmaxf(sqrtf(s0), 1e-12f),
                       1.f / fmaxf(sqrtf(s1), 1e-12f),
                       1.f / fmaxf(sqrtf(s2), 1e-12f),
                       1.f / fmaxf(sqrtf(s3), 1e-12f)};

  float* shf = (float*)&Az[wid][0];
  const int colf = lane & 15, rgrp = lane >> 4;
#define STAGE2(VA, CT)                                                         \
  _Pragma("unroll")                                                            \
  for (int rr = 0; rr < 4; ++rr)                                               \
    shf[(rgrp * 4 + rr) * 64 + (((CT)*16 + colf) ^ (rgrp << 4))] =             \
        VA[rr] * kk[rr];
  STAGE2(v0, 0) STAGE2(v1, 1) STAGE2(v2, 2) STAGE2(v3, 3)
#undef STAGE2
  const int row = lane >> 2, q = lane & 3;
  const int blk = q ^ (row >> 2);
  float* op = out + (size_t)(base + row) * 64 + blk * 16;
#pragma unroll
  for (int e = 0; e < 4; ++e)
    *(float4*)(op + e * 4) = *(const float4*)&shf[row * 64 + q * 16 + e * 4];
}

extern "C" void kernel_launch(void* const* d_in, const int* in_sizes, int n_in,
                              void* d_out, int out_size, void* d_ws, size_t ws_size,
                              hipStream_t stream) {
  const float* ft0;
  const float* W1;
  const float* W2;
  const int*   nbr;
  if (in_sizes[0] == N_NODES * DIM) {          // insertion order
    ft0 = (const float*)d_in[0];
    W1  = (const float*)d_in[1];
    W2  = (const float*)d_in[2];
    nbr = (const int*)d_in[3];
  } else {                                      // alphabetical fallback
    W1  = (const float*)d_in[0];
    W2  = (const float*)d_in[1];
    ft0 = (const float*)d_in[2];
    nbr = (const int*)d_in[3];
  }

  unsigned short* ftb0 = (unsigned short*)d_ws;          // 6.4 MB bf16 ft_lv0
  unsigned short* ft1b = ftb0 + (size_t)N_NODES * DIM;   // 6.4 MB bf16 ft_lv1
  unsigned short* Wb   = ft1b + (size_t)N_NODES * DIM;   // 32 KB W frags
  float* out = (float*)d_out;

  const int n4 = (N_NODES * DIM) / 4;
  cast_bf16<<<dim3((n4 + 255) / 256), dim3(256), 0, stream>>>(ft0, ftb0, n4);
  prep_w<<<dim3(8), dim3(256), 0, stream>>>(W1, W2, Wb);

  const int nblk = (NTILES + 3) / 4;            // 782 blocks x 4 waves
  gcn_mfma1<<<dim3(nblk), dim3(256), 0, stream>>>(ftb0, Wb, nbr, ft1b);
  gcn_mfma2<<<dim3(nblk), dim3(256), 0, stream>>>(ft1b, Wb + 8192, nbr, out);
}

// Round 13
// 114.151 us; speedup vs baseline: 1.9339x; 1.0193x over previous
//
#include <hip/hip_runtime.h>
#include <hip/hip_bf16.h>

// GCN 2-layer, MI355X — MFMA v3.
// v2 (116us) capped at 12 waves/CU (3125 tile-waves / 256 CU): gather latency
// (nbr->17 feature loads, 8 phases) can't be hidden at 3 waves/SIMD. v3 splits
// each 16-node tile across 2 waves (shared LDS A-tile, barrier, redundant
// 16xMFMA, split C-store): 6250 waves, launch_bounds(256,4) => 16 waves/CU,
// and per-wave gather phases halve (4). Tile index scalarized (readfirstlane)
// so nbr index loads become s_load issued ahead.

#define N_NODES 50000
#define DEG 16
#define DIM 64
#define NTILES 3125   // N_NODES / 16

typedef __attribute__((ext_vector_type(8))) short short8;           // 8 bf16
typedef __attribute__((ext_vector_type(8))) unsigned short ushort8; // 16B
typedef __attribute__((ext_vector_type(4))) float f32x4;

__device__ __forceinline__ unsigned short f2b(float f) {  // RNE f32->bf16
  unsigned int u = __float_as_uint(f);
  u = (u + 0x7FFFu + ((u >> 16) & 1u)) >> 16;
  return (unsigned short)u;
}
#define LOF(u) __uint_as_float((u) << 16)
#define HIF(u) __uint_as_float((u) & 0xFFFF0000u)

__global__ void cast_bf16(const float* __restrict__ in, unsigned short* __restrict__ out, int n4) {
  const int i = blockIdx.x * 256 + threadIdx.x;
  if (i < n4) {
    const float4 v = reinterpret_cast<const float4*>(in)[i];
    ushort4 o4;
    o4.x = f2b(v.x); o4.y = f2b(v.y); o4.z = f2b(v.z); o4.w = f2b(v.w);
    reinterpret_cast<ushort4*>(out)[i] = o4;
  }
}

// W -> per-lane MFMA B-fragments (one 16B load per frag at use site).
__global__ void prep_w(const float* __restrict__ W1, const float* __restrict__ W2,
                       unsigned short* __restrict__ Wb) {
  const int task = blockIdx.x * 256 + threadIdx.x;
  if (task >= 2048) return;
  const int which = task >> 10;
  const int f = (task >> 6) & 15;
  const int l = task & 63;
  const int ct = f >> 2, ks = f & 3;
  const int wn = l & 15, wg = l >> 4;
  const float* W = which ? W2 : W1;
  const float* wp = W + (ct * 16 + wn) * 128 + ks * 32 + wg * 8;
  const float4 w0 = *(const float4*)wp;
  const float4 w1 = *(const float4*)(wp + 4);
  ushort8 o;
  o[0] = f2b(w0.x); o[1] = f2b(w0.y); o[2] = f2b(w0.z); o[3] = f2b(w0.w);
  o[4] = f2b(w1.x); o[5] = f2b(w1.y); o[6] = f2b(w1.z); o[7] = f2b(w1.w);
  *(ushort8*)(Wb + ((size_t)(which * 16 + f) * 64 + l) * 8) = o;
}

// Each wave gathers its 4 node-pair phases (8 nodes) into the SHARED tile Azs.
#define GATHER_AND_STAGE_V3()                                                  \
  _Pragma("unroll 2")                                                          \
  for (int p = 0; p < 4; ++p) {                                                \
    const int pp = sub * 4 + p;                                                \
    const int rA = (base + 2 * pp) * DEG;                                      \
    const int4 ia0 = *(const int4*)(nbr + rA);                                 \
    const int4 ia1 = *(const int4*)(nbr + rA + 4);                             \
    const int4 ia2 = *(const int4*)(nbr + rA + 8);                             \
    const int4 ia3 = *(const int4*)(nbr + rA + 12);                            \
    const int4 ib0 = *(const int4*)(nbr + rA + 16);                            \
    const int4 ib1 = *(const int4*)(nbr + rA + 20);                            \
    const int4 ib2 = *(const int4*)(nbr + rA + 24);                            \
    const int4 ib3 = *(const int4*)(nbr + rA + 28);                            \
    const unsigned int un  = ftp[(base + 2 * pp + half) * 32 + c];             \
    const unsigned int v0  = ftp[(half ? ib0.x : ia0.x) * 32 + c];             \
    const unsigned int v1  = ftp[(half ? ib0.y : ia0.y) * 32 + c];             \
    const unsigned int v2  = ftp[(half ? ib0.z : ia0.z) * 32 + c];             \
    const unsigned int v3  = ftp[(half ? ib0.w : ia0.w) * 32 + c];             \
    const unsigned int v4  = ftp[(half ? ib1.x : ia1.x) * 32 + c];             \
    const unsigned int v5  = ftp[(half ? ib1.y : ia1.y) * 32 + c];             \
    const unsigned int v6  = ftp[(half ? ib1.z : ia1.z) * 32 + c];             \
    const unsigned int v7  = ftp[(half ? ib1.w : ia1.w) * 32 + c];             \
    const unsigned int v8  = ftp[(half ? ib2.x : ia2.x) * 32 + c];             \
    const unsigned int v9  = ftp[(half ? ib2.y : ia2.y) * 32 + c];             \
    const unsigned int v10 = ftp[(half ? ib2.z : ia2.z) * 32 + c];             \
    const unsigned int v11 = ftp[(half ? ib2.w : ia2.w) * 32 + c];             \
    const unsigned int v12 = ftp[(half ? ib3.x : ia3.x) * 32 + c];             \
    const unsigned int v13 = ftp[(half ? ib3.y : ia3.y) * 32 + c];             \
    const unsigned int v14 = ftp[(half ? ib3.z : ia3.z) * 32 + c];             \
    const unsigned int v15 = ftp[(half ? ib3.w : ia3.w) * 32 + c];             \
    const float plo = (((LOF(v0) + LOF(v1)) + (LOF(v2) + LOF(v3))) +           \
                       ((LOF(v4) + LOF(v5)) + (LOF(v6) + LOF(v7)))) +          \
                      (((LOF(v8) + LOF(v9)) + (LOF(v10) + LOF(v11))) +         \
                       ((LOF(v12) + LOF(v13)) + (LOF(v14) + LOF(v15))));       \
    const float phi = (((HIF(v0) + HIF(v1)) + (HIF(v2) + HIF(v3))) +           \
                       ((HIF(v4) + HIF(v5)) + (HIF(v6) + HIF(v7)))) +          \
                      (((HIF(v8) + HIF(v9)) + (HIF(v10) + HIF(v11))) +         \
                       ((HIF(v12) + HIF(v13)) + (HIF(v14) + HIF(v15))));       \
    const float nlo = LOF(un), nhi = HIF(un);                                  \
    const float z1lo = nlo + plo, z1hi = nhi + phi;                            \
    const float z2lo = nlo * plo, z2hi = nhi * phi;                            \
    unsigned int z1p, z2p;                                                     \
    asm("v_cvt_pk_bf16_f32 %0, %1, %2" : "=v"(z1p) : "v"(z1lo), "v"(z1hi));    \
    asm("v_cvt_pk_bf16_f32 %0, %1, %2" : "=v"(z2p) : "v"(z2lo), "v"(z2hi));    \
    const int r = 2 * pp + half;                                               \
    const int cs = c ^ ((r & 7) << 2);                                         \
    Azs[r * 64 + cs] = z1p;                                                    \
    Azs[r * 64 + 32 + cs] = z2p;                                               \
  }

#define PRELOAD_W()                                                            \
  short8 Bf[4][4];                                                             \
  {                                                                            \
    const short8* wf = (const short8*)Wb;                                      \
    _Pragma("unroll")                                                          \
    for (int f = 0; f < 16; ++f) Bf[f >> 2][f & 3] = wf[f * 64 + lane];        \
  }

#define MFMA_ACCUM()                                                           \
  f32x4 ac0 = {0.f, 0.f, 0.f, 0.f}, ac1 = ac0, ac2 = ac0, ac3 = ac0;          \
  {                                                                            \
    const int arow = lane & 15, agrp = lane >> 4;                              \
    const int axor = (arow & 7) << 2;                                          \
    _Pragma("unroll")                                                          \
    for (int ks = 0; ks < 4; ++ks) {                                           \
      const short8 a =                                                         \
          *(const short8*)&Azs[arow * 64 + ((ks * 16 + agrp * 4) ^ axor)];     \
      ac0 = __builtin_amdgcn_mfma_f32_16x16x32_bf16(a, Bf[0][ks], ac0, 0, 0, 0);\
      ac1 = __builtin_amdgcn_mfma_f32_16x16x32_bf16(a, Bf[1][ks], ac1, 0, 0, 0);\
      ac2 = __builtin_amdgcn_mfma_f32_16x16x32_bf16(a, Bf[2][ks], ac2, 0, 0, 0);\
      ac3 = __builtin_amdgcn_mfma_f32_16x16x32_bf16(a, Bf[3][ks], ac3, 0, 0, 0);\
    }                                                                          \
  }

__global__ __launch_bounds__(256, 4)
void gcn_mfma1(const unsigned short* __restrict__ ftb,
               const unsigned short* __restrict__ Wb,
               const int* __restrict__ nbr,
               unsigned short* __restrict__ outb) {
  __shared__ unsigned int Az[2][1024];   // 2 tiles/block, 16x128 bf16 each
  const int tid = threadIdx.x;
  const int lane = tid & 63, wid = tid >> 6;
  const int tl = wid >> 1, sub = wid & 1;
  const int t = __builtin_amdgcn_readfirstlane(blockIdx.x * 2 + tl);
  const bool active = (t < NTILES);
  const int base = t * 16;
  const int half = lane >> 5, c = lane & 31;
  const unsigned int* ftp = (const unsigned int*)ftb;
  unsigned int* Azs = &Az[tl][0];

  if (active) { GATHER_AND_STAGE_V3(); }
  PRELOAD_W();
  __syncthreads();                      // A-tile complete (both waves)
  MFMA_ACCUM();                         // inactive waves read junk, never store
  __syncthreads();                      // all MFMA reads done before C overwrite

  if (active) {
    // stage own-half C rows (swizzled), same-wave readback, coalesced store
    unsigned short* sh = (unsigned short*)Azs;
    const int colf = lane & 15, rgrp = lane >> 4;
    if ((rgrp >> 1) == sub) {
#define STG1(AC, CT)                                                           \
      _Pragma("unroll")                                                        \
      for (int rr = 0; rr < 4; ++rr)                                           \
        sh[(rgrp * 4 + rr) * 64 + (((CT)*16 + colf) ^ (rgrp << 4))] =          \
            f2b(fmaxf(AC[rr], 0.f));
      STG1(ac0, 0) STG1(ac1, 1) STG1(ac2, 2) STG1(ac3, 3)
#undef STG1
    }
    const int row = sub * 8 + (lane >> 3), b = lane & 7;
    const int rg = row >> 2;
    const ushort8 d = *(const ushort8*)&sh[row * 64 + ((b ^ (rg << 1)) << 3)];
    *(ushort8*)(outb + (size_t)(base + row) * 64 + b * 8) = d;
  }
}

__global__ __launch_bounds__(256, 4)
void gcn_mfma2(const unsigned short* __restrict__ ftb,
               const unsigned short* __restrict__ Wb,
               const int* __restrict__ nbr,
               float* __restrict__ out) {
  __shared__ unsigned int Az[2][1024];
  const int tid = threadIdx.x;
  const int lane = tid & 63, wid = tid >> 6;
  const int tl = wid >> 1, sub = wid & 1;
  const int t = __builtin_amdgcn_readfirstlane(blockIdx.x * 2 + tl);
  const bool active = (t < NTILES);
  const int base = t * 16;
  const int half = lane >> 5, c = lane & 31;
  const unsigned int* ftp = (const unsigned int*)ftb;
  unsigned int* Azs = &Az[tl][0];

  if (active) { GATHER_AND_STAGE_V3(); }
  PRELOAD_W();
  __syncthreads();
  MFMA_ACCUM();
  __syncthreads();

  if (active) {
    float v0[4], v1[4], v2[4], v3[4];
#pragma unroll
    for (int rr = 0; rr < 4; ++rr) {
      v0[rr] = fmaxf(ac0[rr], 0.f);
      v1[rr] = fmaxf(ac1[rr], 0.f);
      v2[rr] = fmaxf(ac2[rr], 0.f);
      v3[rr] = fmaxf(ac3[rr], 0.f);
    }
    float s0 = v0[0]*v0[0] + v1[0]*v1[0] + v2[0]*v2[0] + v3[0]*v3[0];
    float s1 = v0[1]*v0[1] + v1[1]*v1[1] + v2[1]*v2[1] + v3[1]*v3[1];
    float s2 = v0[2]*v0[2] + v1[2]*v1[2] + v2[2]*v2[2] + v3[2]*v3[2];
    float s3 = v0[3]*v0[3] + v1[3]*v1[3] + v2[3]*v2[3] + v3[3]*v3[3];
#pragma unroll
    for (int w = 1; w < 16; w <<= 1) {   // reduce over 16 col-lanes
      s0 += __shfl_xor(s0, w, 64);
      s1 += __shfl_xor(s1, w, 64);
      s2 += __shfl_xor(s2, w, 64);
      s3 += __shfl_xor(s3, w, 64);
    }
    const float kk[4] = {1.f / fmaxf(sqrtf(s0), 1e-12f),
                         1.f / fmaxf(sqrtf(s1), 1e-12f),
                         1.f / fmaxf(sqrtf(s2), 1e-12f),
                         1.f / fmaxf(sqrtf(s3), 1e-12f)};

    float* shf = (float*)Azs;
    const int colf = lane & 15, rgrp = lane >> 4;
    if ((rgrp >> 1) == sub) {
#define STG2(VA, CT)                                                           \
      _Pragma("unroll")                                                        \
      for (int rr = 0; rr < 4; ++rr)                                           \
        shf[(rgrp * 4 + rr) * 64 + (((CT)*16 + colf) ^ (rgrp << 4))] =         \
            VA[rr] * kk[rr];
      STG2(v0, 0) STG2(v1, 1) STG2(v2, 2) STG2(v3, 3)
#undef STG2
    }
    const int row = sub * 8 + (lane >> 3);
    const int rg = row >> 2;
    float* op = out + (size_t)(base + row) * 64;
#pragma unroll
    for (int e = 0; e < 2; ++e) {
      const int c4 = (lane & 7) * 2 + e;           // float4 chunk within row
      *(float4*)(op + c4 * 4) =
          *(const float4*)&shf[row * 64 + ((c4 ^ (rg << 2)) << 2)];
    }
  }
}

extern "C" void kernel_launch(void* const* d_in, const int* in_sizes, int n_in,
                              void* d_out, int out_size, void* d_ws, size_t ws_size,
                              hipStream_t stream) {
  const float* ft0;
  const float* W1;
  const float* W2;
  const int*   nbr;
  if (in_sizes[0] == N_NODES * DIM) {          // insertion order
    ft0 = (const float*)d_in[0];
    W1  = (const float*)d_in[1];
    W2  = (const float*)d_in[2];
    nbr = (const int*)d_in[3];
  } else {                                      // alphabetical fallback
    W1  = (const float*)d_in[0];
    W2  = (const float*)d_in[1];
    ft0 = (const float*)d_in[2];
    nbr = (const int*)d_in[3];
  }

  unsigned short* ftb0 = (unsigned short*)d_ws;          // 6.4 MB bf16 ft_lv0
  unsigned short* ft1b = ftb0 + (size_t)N_NODES * DIM;   // 6.4 MB bf16 ft_lv1
  unsigned short* Wb   = ft1b + (size_t)N_NODES * DIM;   // 32 KB W frags
  float* out = (float*)d_out;

  const int n4 = (N_NODES * DIM) / 4;
  cast_bf16<<<dim3((n4 + 255) / 256), dim3(256), 0, stream>>>(ft0, ftb0, n4);
  prep_w<<<dim3(8), dim3(256), 0, stream>>>(W1, W2, Wb);

  const int nblk = (NTILES + 1) / 2;            // 1563 blocks x 4 waves (2 tiles)
  gcn_mfma1<<<dim3(nblk), dim3(256), 0, stream>>>(ftb0, Wb, nbr, ft1b);
  gcn_mfma2<<<dim3(nblk), dim3(256), 0, stream>>>(ft1b, Wb + 8192, nbr, out);
}

// Round 16
// 108.100 us; speedup vs baseline: 2.0421x; 1.0560x over previous
//
#include <hip/hip_runtime.h>
#include <hip/hip_bf16.h>

// GCN 2-layer, MI355X — MFMA v4.
// v3 (114us ~= v2's 116) refuted "just add waves": W-frags pinned 64 VGPR/wave
// under a 128 cap -> gather concurrency throttled (spills/serialization). v4:
// W in LDS (frees 64 VGPR), column-split MFMA across the tile's 2 waves (no
// redundant compute, acc 16->8), cross-wave norm combine via LDS, cast+prep
// fused. Target: real 20+ waves/CU and 30+ outstanding gather loads per wave.

#define N_NODES 50000
#define DEG 16
#define DIM 64
#define NTILES 3125
#define CAST_BLOCKS 3125   // 800000 float4s / 256

typedef __attribute__((ext_vector_type(8))) short short8;           // 8 bf16
typedef __attribute__((ext_vector_type(8))) unsigned short ushort8; // 16B
typedef __attribute__((ext_vector_type(4))) float f32x4;
typedef __attribute__((ext_vector_type(4))) unsigned int uint4v;

__device__ __forceinline__ unsigned short f2b(float f) {  // RNE f32->bf16
  unsigned int u = __float_as_uint(f);
  u = (u + 0x7FFFu + ((u >> 16) & 1u)) >> 16;
  return (unsigned short)u;
}
#define LOF(u) __uint_as_float((u) << 16)
#define HIF(u) __uint_as_float((u) & 0xFFFF0000u)

// Fused: ft0 f32->bf16 cast (blocks 0..3124) + W1/W2 -> MFMA B-fragment pack
// (blocks 3125..3132). Frag f=ct*4+ks, lane l: W[ct*16+(l&15)][ks*32+(l>>4)*8+e]
__global__ void prep(const float* __restrict__ ft0,
                     const float* __restrict__ W1, const float* __restrict__ W2,
                     unsigned short* __restrict__ ftb, unsigned short* __restrict__ Wb) {
  const int b = blockIdx.x;
  if (b < CAST_BLOCKS) {
    const int i = b * 256 + threadIdx.x;
    const float4 v = reinterpret_cast<const float4*>(ft0)[i];
    ushort4 o4;
    o4.x = f2b(v.x); o4.y = f2b(v.y); o4.z = f2b(v.z); o4.w = f2b(v.w);
    reinterpret_cast<ushort4*>(ftb)[i] = o4;
  } else {
    const int task = (b - CAST_BLOCKS) * 256 + threadIdx.x;
    if (task >= 2048) return;
    const int which = task >> 10;
    const int f = (task >> 6) & 15;
    const int l = task & 63;
    const int ct = f >> 2, ks = f & 3;
    const float* W = which ? W2 : W1;
    const float* wp = W + (ct * 16 + (l & 15)) * 128 + ks * 32 + (l >> 4) * 8;
    const float4 w0 = *(const float4*)wp;
    const float4 w1 = *(const float4*)(wp + 4);
    ushort8 o;
    o[0] = f2b(w0.x); o[1] = f2b(w0.y); o[2] = f2b(w0.z); o[3] = f2b(w0.w);
    o[4] = f2b(w1.x); o[5] = f2b(w1.y); o[6] = f2b(w1.z); o[7] = f2b(w1.w);
    *(ushort8*)(Wb + ((size_t)(which * 16 + f) * 64 + l) * 8) = o;
  }
}

// Each wave gathers 4 node-pair phases (its 8 rows) into the shared A-tile.
#define GATHER_AND_STAGE()                                                     \
  _Pragma("unroll 2")                                                          \
  for (int p = 0; p < 4; ++p) {                                                \
    const int pp = sub * 4 + p;                                                \
    const int rA = (base + 2 * pp) * DEG;                                      \
    const int4 ia0 = *(const int4*)(nbr + rA);                                 \
    const int4 ia1 = *(const int4*)(nbr + rA + 4);                             \
    const int4 ia2 = *(const int4*)(nbr + rA + 8);                             \
    const int4 ia3 = *(const int4*)(nbr + rA + 12);                            \
    const int4 ib0 = *(const int4*)(nbr + rA + 16);                            \
    const int4 ib1 = *(const int4*)(nbr + rA + 20);                            \
    const int4 ib2 = *(const int4*)(nbr + rA + 24);                            \
    const int4 ib3 = *(const int4*)(nbr + rA + 28);                            \
    const unsigned int un  = ftp[(base + 2 * pp + half) * 32 + c];             \
    const unsigned int v0  = ftp[(half ? ib0.x : ia0.x) * 32 + c];             \
    const unsigned int v1  = ftp[(half ? ib0.y : ia0.y) * 32 + c];             \
    const unsigned int v2  = ftp[(half ? ib0.z : ia0.z) * 32 + c];             \
    const unsigned int v3  = ftp[(half ? ib0.w : ia0.w) * 32 + c];             \
    const unsigned int v4  = ftp[(half ? ib1.x : ia1.x) * 32 + c];             \
    const unsigned int v5  = ftp[(half ? ib1.y : ia1.y) * 32 + c];             \
    const unsigned int v6  = ftp[(half ? ib1.z : ia1.z) * 32 + c];             \
    const unsigned int v7  = ftp[(half ? ib1.w : ia1.w) * 32 + c];             \
    const unsigned int v8  = ftp[(half ? ib2.x : ia2.x) * 32 + c];             \
    const unsigned int v9  = ftp[(half ? ib2.y : ia2.y) * 32 + c];             \
    const unsigned int v10 = ftp[(half ? ib2.z : ia2.z) * 32 + c];             \
    const unsigned int v11 = ftp[(half ? ib2.w : ia2.w) * 32 + c];             \
    const unsigned int v12 = ftp[(half ? ib3.x : ia3.x) * 32 + c];             \
    const unsigned int v13 = ftp[(half ? ib3.y : ia3.y) * 32 + c];             \
    const unsigned int v14 = ftp[(half ? ib3.z : ia3.z) * 32 + c];             \
    const unsigned int v15 = ftp[(half ? ib3.w : ia3.w) * 32 + c];             \
    const float plo = (((LOF(v0) + LOF(v1)) + (LOF(v2) + LOF(v3))) +           \
                       ((LOF(v4) + LOF(v5)) + (LOF(v6) + LOF(v7)))) +          \
                      (((LOF(v8) + LOF(v9)) + (LOF(v10) + LOF(v11))) +         \
                       ((LOF(v12) + LOF(v13)) + (LOF(v14) + LOF(v15))));       \
    const float phi = (((HIF(v0) + HIF(v1)) + (HIF(v2) + HIF(v3))) +           \
                       ((HIF(v4) + HIF(v5)) + (HIF(v6) + HIF(v7)))) +          \
                      (((HIF(v8) + HIF(v9)) + (HIF(v10) + HIF(v11))) +         \
                       ((HIF(v12) + HIF(v13)) + (HIF(v14) + HIF(v15))));       \
    const float nlo = LOF(un), nhi = HIF(un);                                  \
    const float z1lo = nlo + plo, z1hi = nhi + phi;                            \
    const float z2lo = nlo * plo, z2hi = nhi * phi;                            \
    unsigned int z1p, z2p;                                                     \
    asm("v_cvt_pk_bf16_f32 %0, %1, %2" : "=v"(z1p) : "v"(z1lo), "v"(z1hi));    \
    asm("v_cvt_pk_bf16_f32 %0, %1, %2" : "=v"(z2p) : "v"(z2lo), "v"(z2hi));    \
    const int r = 2 * pp + half;                                               \
    const int cs = c ^ ((r & 7) << 2);                                         \
    Azs[r * 64 + cs] = z1p;                                                    \
    Azs[r * 64 + 32 + cs] = z2p;                                               \
  }

#define LOAD_WLDS()                                                            \
  {                                                                            \
    const uint4v* src = (const uint4v*)Wb;                                     \
    uint4v* dst = (uint4v*)Wlds;                                               \
    _Pragma("unroll")                                                          \
    for (int i = 0; i < 4; ++i) dst[i * 256 + tid] = src[i * 256 + tid];       \
  }

// Each wave computes its 2 column-tiles (ct = sub*2 + {0,1}); B from LDS.
#define MFMA_ACCUM()                                                           \
  f32x4 ac0 = {0.f, 0.f, 0.f, 0.f}, ac1 = ac0;                                \
  {                                                                            \
    const int arow = lane & 15, agrp = lane >> 4;                              \
    const int axor = (arow & 7) << 2;                                          \
    const short8* wlds8 = (const short8*)Wlds;                                 \
    _Pragma("unroll")                                                          \
    for (int ks = 0; ks < 4; ++ks) {                                           \
      const short8 a =                                                         \
          *(const short8*)&Azs[arow * 64 + ((ks * 16 + agrp * 4) ^ axor)];     \
      const short8 b0 = wlds8[((sub * 2 + 0) * 4 + ks) * 64 + lane];           \
      const short8 b1 = wlds8[((sub * 2 + 1) * 4 + ks) * 64 + lane];           \
      ac0 = __builtin_amdgcn_mfma_f32_16x16x32_bf16(a, b0, ac0, 0, 0, 0);      \
      ac1 = __builtin_amdgcn_mfma_f32_16x16x32_bf16(a, b1, ac1, 0, 0, 0);      \
    }                                                                          \
  }

__global__ __launch_bounds__(256, 4)
void gcn_mfma1(const unsigned short* __restrict__ ftb,
               const unsigned short* __restrict__ Wb,
               const int* __restrict__ nbr,
               unsigned short* __restrict__ outb) {
  __shared__ unsigned int Wlds[4096];     // 16 KB: prepacked B frags
  __shared__ unsigned int Az[2][1024];    // 2 tiles x 16x128 bf16
  const int tid = threadIdx.x;
  const int lane = tid & 63, wid = tid >> 6;
  const int tl = wid >> 1, sub = wid & 1;
  const int t = __builtin_amdgcn_readfirstlane(blockIdx.x * 2 + tl);
  const bool active = (t < NTILES);
  const int base = t * 16;
  const int half = lane >> 5, c = lane & 31;
  const unsigned int* ftp = (const unsigned int*)ftb;
  unsigned int* Azs = &Az[tl][0];

  LOAD_WLDS();
  if (active) { GATHER_AND_STAGE(); }
  __syncthreads();                      // Wlds + A-tile ready
  MFMA_ACCUM();
  __syncthreads();                      // all A/W reads done before reuse

  if (active) {
    // wave's 32-col slab: [16 rows][32 cols] bf16 = 1 KB in its A-tile half
    unsigned short* slab = (unsigned short*)Azs + sub * 512;
    const int colf = lane & 15, rgrp = lane >> 4;
#pragma unroll
    for (int rr = 0; rr < 4; ++rr) {
      slab[(rgrp * 4 + rr) * 32 + colf]      = f2b(fmaxf(ac0[rr], 0.f));
      slab[(rgrp * 4 + rr) * 32 + 16 + colf] = f2b(fmaxf(ac1[rr], 0.f));
    }
    const int row = lane >> 2, chunk = lane & 3;
    const ushort8 d = *(const ushort8*)&slab[row * 32 + chunk * 8];
    *(ushort8*)(outb + (size_t)(base + row) * 64 + sub * 32 + chunk * 8) = d;
  }
}

__global__ __launch_bounds__(256, 4)
void gcn_mfma2(const unsigned short* __restrict__ ftb,
               const unsigned short* __restrict__ Wb,
               const int* __restrict__ nbr,
               float* __restrict__ out) {
  __shared__ unsigned int Wlds[4096];
  __shared__ unsigned int Az[2][1024];
  __shared__ float sP[2][2][16];          // [tile][sub][row] partial sq-sums
  const int tid = threadIdx.x;
  const int lane = tid & 63, wid = tid >> 6;
  const int tl = wid >> 1, sub = wid & 1;
  const int t = __builtin_amdgcn_readfirstlane(blockIdx.x * 2 + tl);
  const bool active = (t < NTILES);
  const int base = t * 16;
  const int half = lane >> 5, c = lane & 31;
  const unsigned int* ftp = (const unsigned int*)ftb;
  unsigned int* Azs = &Az[tl][0];

  LOAD_WLDS();
  if (active) { GATHER_AND_STAGE(); }
  __syncthreads();
  MFMA_ACCUM();

  float v0[4], v1[4];
  const int colf = lane & 15, rgrp = lane >> 4;
  if (active) {
    float s0, s1, s2, s3;
#pragma unroll
    for (int rr = 0; rr < 4; ++rr) {
      v0[rr] = fmaxf(ac0[rr], 0.f);
      v1[rr] = fmaxf(ac1[rr], 0.f);
    }
    s0 = v0[0] * v0[0] + v1[0] * v1[0];
    s1 = v0[1] * v0[1] + v1[1] * v1[1];
    s2 = v0[2] * v0[2] + v1[2] * v1[2];
    s3 = v0[3] * v0[3] + v1[3] * v1[3];
#pragma unroll
    for (int w = 1; w < 16; w <<= 1) {   // reduce over the 16 col-lanes
      s0 += __shfl_xor(s0, w, 64);
      s1 += __shfl_xor(s1, w, 64);
      s2 += __shfl_xor(s2, w, 64);
      s3 += __shfl_xor(s3, w, 64);
    }
    if (colf == 0) {
      sP[tl][sub][rgrp * 4 + 0] = s0;
      sP[tl][sub][rgrp * 4 + 1] = s1;
      sP[tl][sub][rgrp * 4 + 2] = s2;
      sP[tl][sub][rgrp * 4 + 3] = s3;
    }
  }
  __syncthreads();                      // A/W reads done + sP complete

  if (active) {
    float kk[4];
#pragma unroll
    for (int rr = 0; rr < 4; ++rr) {
      const float s = sP[tl][0][rgrp * 4 + rr] + sP[tl][1][rgrp * 4 + rr];
      kk[rr] = 1.f / fmaxf(sqrtf(s), 1e-12f);
    }
    float* slab = (float*)Azs + sub * 512;  // [16 rows][32 cols] f32 = 2 KB
#pragma unroll
    for (int rr = 0; rr < 4; ++rr) {
      slab[(rgrp * 4 + rr) * 32 + colf]      = v0[rr] * kk[rr];
      slab[(rgrp * 4 + rr) * 32 + 16 + colf] = v1[rr] * kk[rr];
    }
    const int row = lane >> 2, chunk = lane & 3;
    float* op = out + (size_t)(base + row) * 64 + sub * 32 + chunk * 4;
    *(float4*)op        = *(const float4*)&slab[row * 32 + chunk * 4];
    *(float4*)(op + 16) = *(const float4*)&slab[row * 32 + chunk * 4 + 16];
  }
}

extern "C" void kernel_launch(void* const* d_in, const int* in_sizes, int n_in,
                              void* d_out, int out_size, void* d_ws, size_t ws_size,
                              hipStream_t stream) {
  const float* ft0;
  const float* W1;
  const float* W2;
  const int*   nbr;
  if (in_sizes[0] == N_NODES * DIM) {          // insertion order
    ft0 = (const float*)d_in[0];
    W1  = (const float*)d_in[1];
    W2  = (const float*)d_in[2];
    nbr = (const int*)d_in[3];
  } else {                                      // alphabetical fallback
    W1  = (const float*)d_in[0];
    W2  = (const float*)d_in[1];
    ft0 = (const float*)d_in[2];
    nbr = (const int*)d_in[3];
  }

  unsigned short* ftb0 = (unsigned short*)d_ws;          // 6.4 MB bf16 ft_lv0
  unsigned short* ft1b = ftb0 + (size_t)N_NODES * DIM;   // 6.4 MB bf16 ft_lv1
  unsigned short* Wb   = ft1b + (size_t)N_NODES * DIM;   // 32 KB W frags
  float* out = (float*)d_out;

  prep<<<dim3(CAST_BLOCKS + 8), dim3(256), 0, stream>>>(ft0, W1, W2, ftb0, Wb);

  const int nblk = (NTILES + 1) / 2;            // 1563 blocks x 4 waves (2 tiles)
  gcn_mfma1<<<dim3(nblk), dim3(256), 0, stream>>>(ftb0, Wb, nbr, ft1b);
  gcn_mfma2<<<dim3(nblk), dim3(256), 0, stream>>>(ft1b, Wb + 8192, nbr, out);
}